// Round 14
// baseline (963.927 us; speedup 1.0000x reference)
//
#include <hip/hip_runtime.h>
#include <hip/hip_bf16.h>
#include <cstddef>
#include <cstdint>

#define NNODES 50000
#define NR 3
#define NE 800000
#define HIDF 128
#define OUTF 64
#define NEG_SLOPE 0.01f
#define SCAN_T 1024
#define NCHUNK ((NNODES + SCAN_T - 1) / SCAN_T)   // 49
#define KTOT (NR * HIDF)                          // 384
#define KU (KTOT / 2)                             // 192 uints per row
#define RN (NR * NNODES)                          // 150000
#define CHN 25000                                 // chunk node range (100KB u32 LDS)
#define NCH ((NNODES + CHN - 1) / CHN)            // 2
#define CTH 1024                                  // count/fill block size
#define NSEG 32                                   // edge segments
#define SEGE (NE / NSEG)                          // 25000 edges per segment

// bf16 helpers: packed ushort2-in-uint, round-to-nearest-even on pack
__device__ __forceinline__ float bf_lo(uint v) { return __uint_as_float(v << 16); }
__device__ __forceinline__ float bf_hi(uint v) { return __uint_as_float(v & 0xffff0000u); }
__device__ __forceinline__ uint bf_rne(float f) {
    uint u = __float_as_uint(f);
    return (u + 0x7fffu + ((u >> 16) & 1u)) >> 16;
}
__device__ __forceinline__ uint bf_pack(float a, float b) {
    return bf_rne(a) | (bf_rne(b) << 16);
}

typedef short bf16x8 __attribute__((ext_vector_type(8)));
typedef float f32x4 __attribute__((ext_vector_type(4)));
__device__ __forceinline__ bf16x8 as_bf(uint4 v) { return __builtin_bit_cast(bf16x8, v); }

// nontemporal 8B edge-record load: (src, w) without polluting L2
__device__ __forceinline__ void nt_edge(const int2* p, int& s, float& w) {
    unsigned long long e = __builtin_nontemporal_load((const unsigned long long*)p);
    s = (int)(uint)(e & 0xffffffffull);
    w = __uint_as_float((uint)(e >> 32));
}

// ---------------------------------------------------------------------------
// 0) Cast x (fp32) -> packed bf16 rows
// ---------------------------------------------------------------------------
__global__ __launch_bounds__(256) void k_cast_x(const float* __restrict__ x,
                                                uint* __restrict__ xb) {
    int i = blockIdx.x * blockDim.x + threadIdx.x;   // uint index: N*64
    if (i >= NNODES * (HIDF / 2)) return;
    float2 v = *(const float2*)(x + (size_t)i * 2);
    xb[i] = bf_pack(v.x, v.y);
}

// ---------------------------------------------------------------------------
// 0b) Cast all 5 layers' W (fp32 [r][k][n]) -> bf16 transposed wbT[l][n][kpair]
// ---------------------------------------------------------------------------
__global__ __launch_bounds__(256) void k_cast_w(const float* __restrict__ W0,
                                                const float* __restrict__ Wl,
                                                uint* __restrict__ wbT) {
    int idx = blockIdx.x * blockDim.x + threadIdx.x;
    if (idx >= 5 * HIDF * KU) return;
    int l = idx / (HIDF * KU);
    int rem = idx - l * (HIDF * KU);
    int t = rem / HIDF;          // uint-k index 0..191
    int n = rem - t * HIDF;      // col, fastest -> coalesced reads
    int r = t / 64;
    int kk = (t - r * 64) * 2;   // even k within relation block
    const float* Wsrc = (l == 0) ? W0 : Wl + (size_t)(l - 1) * NR * HIDF * HIDF;
    const float* wp = Wsrc + ((size_t)r * HIDF + kk) * HIDF + n;
    float a = wp[0];
    float b = wp[HIDF];
    wbT[(size_t)l * HIDF * KU + (size_t)n * KU + t] = bf_pack(a, b);
}

// ---------------------------------------------------------------------------
// 1) Segmented chunk-scan histograms -- NO global atomics (round-9 win).
// ---------------------------------------------------------------------------
__global__ __launch_bounds__(CTH) void k_seg_count(const int* __restrict__ esrc,
                                                   const int* __restrict__ edst,
                                                   int* __restrict__ sc_out,
                                                   int* __restrict__ sc_in) {
    __shared__ int cnt[CHN];
    int bid = blockIdx.x;                    // 0 .. 2*NR*NCH*NSEG-1
    int role = bid / (NR * NCH * NSEG);      // 0: dst counts, 1: src counts
    int rem = bid - role * (NR * NCH * NSEG);
    int r = rem / (NCH * NSEG);
    int rem2 = rem - r * (NCH * NSEG);
    int c = rem2 / NSEG;
    int seg = rem2 - c * NSEG;
    int lo = c * CHN;
    int hi = lo + CHN; if (hi > NNODES) hi = NNODES;
    int span = hi - lo;
    const int* arr = (role ? esrc : edst) + (size_t)r * NE + (size_t)seg * SEGE;

    for (int i = threadIdx.x; i < CHN; i += CTH) cnt[i] = 0;
    __syncthreads();

    int base = threadIdx.x * 4;
    for (int it = 0; it < SEGE; it += CTH * 4) {
        int idx = it + base;
        if (idx < SEGE) {                    // SEGE%4==0 -> full int4 valid
            int4 v = *(const int4*)(arr + idx);
            if ((unsigned)(v.x - lo) < (unsigned)span) atomicAdd(&cnt[v.x - lo], 1);
            if ((unsigned)(v.y - lo) < (unsigned)span) atomicAdd(&cnt[v.y - lo], 1);
            if ((unsigned)(v.z - lo) < (unsigned)span) atomicAdd(&cnt[v.z - lo], 1);
            if ((unsigned)(v.w - lo) < (unsigned)span) atomicAdd(&cnt[v.w - lo], 1);
        }
    }
    __syncthreads();

    int* dst = (role ? sc_out : sc_in) + (size_t)seg * RN + r * NNODES;
    for (int i = threadIdx.x; i < span; i += CTH) dst[lo + i] = cnt[i];
}

// ---------------------------------------------------------------------------
// 2) Merge segments: deg_in totals, per-(node,seg) exclusive prefix, norms.
// ---------------------------------------------------------------------------
__global__ __launch_bounds__(256) void k_merge(const int* __restrict__ sc_out,
                                               const int* __restrict__ sc_in,
                                               int* __restrict__ deg_in,
                                               int* __restrict__ xsoff,
                                               float* __restrict__ out_norm,
                                               float* __restrict__ in_norm) {
    int idx = blockIdx.x * blockDim.x + threadIdx.x;
    if (idx >= RN) return;
    int so = 0;
#pragma unroll
    for (int s = 0; s < NSEG; ++s) so += sc_out[(size_t)s * RN + idx];
    int si = 0;
#pragma unroll
    for (int s = 0; s < NSEG; ++s) {
        xsoff[(size_t)s * RN + idx] = si;
        si += sc_in[(size_t)s * RN + idx];
    }
    deg_in[idx] = si;
    out_norm[idx] = rsqrtf((float)(so > 1 ? so : 1));
    in_norm[idx]  = rsqrtf((float)(si > 1 ? si : 1));
}

// ---------------------------------------------------------------------------
// 3) CSR build: per-chunk inclusive scan -> chunk sums -> offsets -> add
// ---------------------------------------------------------------------------
__global__ __launch_bounds__(SCAN_T) void k_scan1(const int* __restrict__ deg_in,
                                                  int* __restrict__ row_ptr,
                                                  int* __restrict__ csums) {
    __shared__ int buf[SCAN_T];
    int r = blockIdx.x / NCHUNK;
    int c = blockIdx.x % NCHUNK;
    int tid = threadIdx.x;
    int i = c * SCAN_T + tid;
    int v = (i < NNODES) ? deg_in[r * NNODES + i] : 0;
    buf[tid] = v;
    __syncthreads();
    for (int off = 1; off < SCAN_T; off <<= 1) {
        int t = (tid >= off) ? buf[tid - off] : 0;
        __syncthreads();
        buf[tid] += t;
        __syncthreads();
    }
    if (i < NNODES) row_ptr[r * (NNODES + 1) + i + 1] = buf[tid];
    if (tid == SCAN_T - 1) csums[r * NCHUNK + c] = buf[SCAN_T - 1];
}

__global__ void k_scan2(const int* __restrict__ csums, int* __restrict__ coffs) {
    int r = threadIdx.x;
    if (r >= NR) return;
    int run = 0;
    for (int c = 0; c < NCHUNK; ++c) {
        coffs[r * NCHUNK + c] = run;
        run += csums[r * NCHUNK + c];
    }
}

__global__ __launch_bounds__(SCAN_T) void k_scan3(int* __restrict__ row_ptr,
                                                  const int* __restrict__ coffs) {
    int r = blockIdx.x / NCHUNK;
    int c = blockIdx.x % NCHUNK;
    int tid = threadIdx.x;
    int i = c * SCAN_T + tid;
    int off = coffs[r * NCHUNK + c];
    if (i < NNODES) row_ptr[r * (NNODES + 1) + i + 1] += off;
    if (tid == 0 && c == 0) row_ptr[r * (NNODES + 1)] = 0;
}

// ---------------------------------------------------------------------------
// 3c) Fuse row_ptr into xsoff (in-place): xsoff[seg][r][n] += row_ptr[r][n].
// ---------------------------------------------------------------------------
__global__ __launch_bounds__(256) void k_rpx(const int* __restrict__ row_ptr,
                                             int* __restrict__ xsoff) {
    int idx = blockIdx.x * blockDim.x + threadIdx.x;   // over NSEG*RN
    if (idx >= NSEG * RN) return;
    int rn = idx % RN;
    int r = rn / NNODES;
    int n = rn - r * NNODES;
    xsoff[idx] += row_ptr[r * (NNODES + 1) + n];
}

// ---------------------------------------------------------------------------
// 3b) Segmented chunk-scan CSR fill -- atomic-free.
//     slot = rpx[seg][d] + LDS-counter position. Writes (src, out_norm[src]).
// ---------------------------------------------------------------------------
__global__ __launch_bounds__(CTH) void k_seg_fill(const int* __restrict__ esrc,
                                                  const int* __restrict__ edst,
                                                  const int* __restrict__ rpx,
                                                  const float* __restrict__ out_norm,
                                                  int2* __restrict__ csr_sw) {
    __shared__ int cur[CHN];
    int bid = blockIdx.x;                    // 0 .. NR*NCH*NSEG-1
    int r = bid / (NCH * NSEG);
    int rem = bid - r * (NCH * NSEG);
    int c = rem / NSEG;
    int seg = rem - c * NSEG;
    int lo = c * CHN;
    int hi = lo + CHN; if (hi > NNODES) hi = NNODES;
    int span = hi - lo;
    const int* sarr = esrc + (size_t)r * NE + (size_t)seg * SEGE;
    const int* darr = edst + (size_t)r * NE + (size_t)seg * SEGE;
    const int* xs = rpx + (size_t)seg * RN + r * NNODES;
    const float* on = out_norm + r * NNODES;
    int2* cs = csr_sw + (size_t)r * NE;

    for (int i = threadIdx.x; i < CHN; i += CTH) cur[i] = 0;
    __syncthreads();

    int base = threadIdx.x * 4;
    for (int it = 0; it < SEGE; it += CTH * 4) {
        int idx = it + base;
        if (idx < SEGE) {
            int4 d = *(const int4*)(darr + idx);
            int4 s = *(const int4*)(sarr + idx);
            if ((unsigned)(d.x - lo) < (unsigned)span) {
                int p = atomicAdd(&cur[d.x - lo], 1);
                cs[xs[d.x] + p] = make_int2(s.x, __float_as_int(on[s.x]));
            }
            if ((unsigned)(d.y - lo) < (unsigned)span) {
                int p = atomicAdd(&cur[d.y - lo], 1);
                cs[xs[d.y] + p] = make_int2(s.y, __float_as_int(on[s.y]));
            }
            if ((unsigned)(d.z - lo) < (unsigned)span) {
                int p = atomicAdd(&cur[d.z - lo], 1);
                cs[xs[d.z] + p] = make_int2(s.z, __float_as_int(on[s.z]));
            }
            if ((unsigned)(d.w - lo) < (unsigned)span) {
                int p = atomicAdd(&cur[d.w - lo], 1);
                cs[xs[d.w] + p] = make_int2(s.w, __float_as_int(on[s.w]));
            }
        }
    }
}

// ---------------------------------------------------------------------------
// 4) Aggregation (round-9 shape). ROUND-14 CHANGE: edge-record loads are
//    NON-TEMPORAL -- the 19.2MB csr stream is read exactly once per dispatch
//    and was evicting the 12.8MB h gather working set from L2. Math order
//    identical to round 13 -> bitwise-identical output.
// ---------------------------------------------------------------------------
__global__ __launch_bounds__(256) void k_aggregate(const uint* __restrict__ hin,
                                                   const float* __restrict__ in_norm,
                                                   const int* __restrict__ row_ptr,
                                                   const int2* __restrict__ csr_sw,
                                                   uint* __restrict__ aggb) {
    int wave = blockIdx.x * 4 + (threadIdx.x >> 6);
    if (wave >= RN) return;
    int r = wave / NNODES;
    int n = wave - r * NNODES;
    int lane = threadIdx.x & 63;
    int quarter = lane >> 4;
    int sub = lane & 15;
    int start = row_ptr[r * (NNODES + 1) + n];
    int end   = row_ptr[r * (NNODES + 1) + n + 1];
    const int2* cw = csr_sw + (size_t)r * NE;

    float acc[8];
#pragma unroll
    for (int k = 0; k < 8; ++k) acc[k] = 0.f;

    int i = start;
    int last = end - 1;
    for (; i + 16 <= end; i += 16) {
        int s0, s1, s2, s3;
        float w0, w1, w2, w3;
        nt_edge(cw + i + quarter, s0, w0);
        nt_edge(cw + i + 4 + quarter, s1, w1);
        nt_edge(cw + i + 8 + quarter, s2, w2);
        nt_edge(cw + i + 12 + quarter, s3, w3);
        uint4 v0 = *(const uint4*)(hin + (size_t)s0 * (HIDF / 2) + sub * 4);
        uint4 v1 = *(const uint4*)(hin + (size_t)s1 * (HIDF / 2) + sub * 4);
        uint4 v2 = *(const uint4*)(hin + (size_t)s2 * (HIDF / 2) + sub * 4);
        uint4 v3 = *(const uint4*)(hin + (size_t)s3 * (HIDF / 2) + sub * 4);
        acc[0] = fmaf(w0, bf_lo(v0.x), acc[0]); acc[1] = fmaf(w0, bf_hi(v0.x), acc[1]);
        acc[2] = fmaf(w0, bf_lo(v0.y), acc[2]); acc[3] = fmaf(w0, bf_hi(v0.y), acc[3]);
        acc[4] = fmaf(w0, bf_lo(v0.z), acc[4]); acc[5] = fmaf(w0, bf_hi(v0.z), acc[5]);
        acc[6] = fmaf(w0, bf_lo(v0.w), acc[6]); acc[7] = fmaf(w0, bf_hi(v0.w), acc[7]);
        acc[0] = fmaf(w1, bf_lo(v1.x), acc[0]); acc[1] = fmaf(w1, bf_hi(v1.x), acc[1]);
        acc[2] = fmaf(w1, bf_lo(v1.y), acc[2]); acc[3] = fmaf(w1, bf_hi(v1.y), acc[3]);
        acc[4] = fmaf(w1, bf_lo(v1.z), acc[4]); acc[5] = fmaf(w1, bf_hi(v1.z), acc[5]);
        acc[6] = fmaf(w1, bf_lo(v1.w), acc[6]); acc[7] = fmaf(w1, bf_hi(v1.w), acc[7]);
        acc[0] = fmaf(w2, bf_lo(v2.x), acc[0]); acc[1] = fmaf(w2, bf_hi(v2.x), acc[1]);
        acc[2] = fmaf(w2, bf_lo(v2.y), acc[2]); acc[3] = fmaf(w2, bf_hi(v2.y), acc[3]);
        acc[4] = fmaf(w2, bf_lo(v2.z), acc[4]); acc[5] = fmaf(w2, bf_hi(v2.z), acc[5]);
        acc[6] = fmaf(w2, bf_lo(v2.w), acc[6]); acc[7] = fmaf(w2, bf_hi(v2.w), acc[7]);
        acc[0] = fmaf(w3, bf_lo(v3.x), acc[0]); acc[1] = fmaf(w3, bf_hi(v3.x), acc[1]);
        acc[2] = fmaf(w3, bf_lo(v3.y), acc[2]); acc[3] = fmaf(w3, bf_hi(v3.y), acc[3]);
        acc[4] = fmaf(w3, bf_lo(v3.z), acc[4]); acc[5] = fmaf(w3, bf_hi(v3.z), acc[5]);
        acc[6] = fmaf(w3, bf_lo(v3.w), acc[6]); acc[7] = fmaf(w3, bf_hi(v3.w), acc[7]);
    }
    for (; i + 8 <= end; i += 8) {
        int sA, sB;
        float wA, wB;
        nt_edge(cw + i + quarter, sA, wA);
        nt_edge(cw + i + 4 + quarter, sB, wB);
        uint4 vA = *(const uint4*)(hin + (size_t)sA * (HIDF / 2) + sub * 4);
        uint4 vB = *(const uint4*)(hin + (size_t)sB * (HIDF / 2) + sub * 4);
        acc[0] = fmaf(wA, bf_lo(vA.x), acc[0]); acc[1] = fmaf(wA, bf_hi(vA.x), acc[1]);
        acc[2] = fmaf(wA, bf_lo(vA.y), acc[2]); acc[3] = fmaf(wA, bf_hi(vA.y), acc[3]);
        acc[4] = fmaf(wA, bf_lo(vA.z), acc[4]); acc[5] = fmaf(wA, bf_hi(vA.z), acc[5]);
        acc[6] = fmaf(wA, bf_lo(vA.w), acc[6]); acc[7] = fmaf(wA, bf_hi(vA.w), acc[7]);
        acc[0] = fmaf(wB, bf_lo(vB.x), acc[0]); acc[1] = fmaf(wB, bf_hi(vB.x), acc[1]);
        acc[2] = fmaf(wB, bf_lo(vB.y), acc[2]); acc[3] = fmaf(wB, bf_hi(vB.y), acc[3]);
        acc[4] = fmaf(wB, bf_lo(vB.z), acc[4]); acc[5] = fmaf(wB, bf_hi(vB.z), acc[5]);
        acc[6] = fmaf(wB, bf_lo(vB.w), acc[6]); acc[7] = fmaf(wB, bf_hi(vB.w), acc[7]);
    }
    for (; i < end; i += 4) {
        int e_idx = i + quarter;
        bool live = e_idx < end;
        int s;
        float w;
        nt_edge(cw + (live ? e_idx : last), s, w);
        if (!live) w = 0.f;
        uint4 v = *(const uint4*)(hin + (size_t)s * (HIDF / 2) + sub * 4);
        acc[0] = fmaf(w, bf_lo(v.x), acc[0]); acc[1] = fmaf(w, bf_hi(v.x), acc[1]);
        acc[2] = fmaf(w, bf_lo(v.y), acc[2]); acc[3] = fmaf(w, bf_hi(v.y), acc[3]);
        acc[4] = fmaf(w, bf_lo(v.z), acc[4]); acc[5] = fmaf(w, bf_hi(v.z), acc[5]);
        acc[6] = fmaf(w, bf_lo(v.w), acc[6]); acc[7] = fmaf(w, bf_hi(v.w), acc[7]);
    }

    // reduce across the 4 quarters (feats identical at same sub)
#pragma unroll
    for (int k = 0; k < 8; ++k) {
        acc[k] += __shfl_xor(acc[k], 16);
        acc[k] += __shfl_xor(acc[k], 32);
    }

    if (quarter == 0) {
        float wn = in_norm[r * NNODES + n];
        uint4 pk;
        pk.x = bf_pack(acc[0] * wn, acc[1] * wn);
        pk.y = bf_pack(acc[2] * wn, acc[3] * wn);
        pk.z = bf_pack(acc[4] * wn, acc[5] * wn);
        pk.w = bf_pack(acc[6] * wn, acc[7] * wn);
        *(uint4*)(aggb + (size_t)n * KU + r * (HIDF / 2) + sub * 4) = pk;
    }
}

// ---------------------------------------------------------------------------
// 5) Per-layer matmul, bf16 MFMA (direct-global fragments, no LDS):
//    h = act( (1/3) * aggb[N,384] @ wbT^T + bmean ), output row-major u16 bf16.
// ---------------------------------------------------------------------------
__global__ __launch_bounds__(256) void k_conv_mm(const uint* __restrict__ aggb,
                                                 const uint* __restrict__ wbT,
                                                 const float* __restrict__ bias,
                                                 ushort* __restrict__ hout,
                                                 int act) {
    int wv   = threadIdx.x >> 6;
    int lane = threadIdx.x & 63;
    int lrow = lane & 15;
    int kgrp = lane >> 4;
    int rb = blockIdx.x * 128 + wv * 32;

    f32x4 acc[2][8];
#pragma unroll
    for (int m = 0; m < 2; ++m)
#pragma unroll
        for (int nr = 0; nr < 8; ++nr) acc[m][nr] = (f32x4){0.f, 0.f, 0.f, 0.f};

    int row0 = rb + lrow;
    int row1 = rb + 16 + lrow;
    bool v0 = row0 < NNODES;
    bool v1 = row1 < NNODES;
    const uint* a0p = aggb + (size_t)row0 * KU + kgrp * 4;
    const uint* a1p = aggb + (size_t)row1 * KU + kgrp * 4;
    const uint* bp  = wbT + (size_t)lrow * KU + kgrp * 4;
    const uint4 za = make_uint4(0u, 0u, 0u, 0u);

#pragma unroll
    for (int ks = 0; ks < KTOT / 32; ++ks) {
        uint4 ua0 = v0 ? *(const uint4*)(a0p + ks * 16) : za;
        uint4 ua1 = v1 ? *(const uint4*)(a1p + ks * 16) : za;
        bf16x8 af0 = as_bf(ua0);
        bf16x8 af1 = as_bf(ua1);
#pragma unroll
        for (int nr = 0; nr < 8; ++nr) {
            uint4 ub = *(const uint4*)(bp + (size_t)nr * (16 * KU) + ks * 16);
            bf16x8 bf = as_bf(ub);
            acc[0][nr] = __builtin_amdgcn_mfma_f32_16x16x32_bf16(af0, bf, acc[0][nr], 0, 0, 0);
            acc[1][nr] = __builtin_amdgcn_mfma_f32_16x16x32_bf16(af1, bf, acc[1][nr], 0, 0, 0);
        }
    }

    const float inv3 = 1.f / 3.f;
#pragma unroll
    for (int nr = 0; nr < 8; ++nr) {
        int col = nr * 16 + lrow;
        float bm = (bias[col] + bias[HIDF + col] + bias[2 * HIDF + col]) * inv3;
#pragma unroll
        for (int m = 0; m < 2; ++m) {
            int rbase = rb + m * 16 + kgrp * 4;
#pragma unroll
            for (int i = 0; i < 4; ++i) {
                int row = rbase + i;
                if (row >= NNODES) continue;
                float t = acc[m][nr][i] * inv3 + bm;
                if (act) t = (t > 0.f) ? t : NEG_SLOPE * t;
                hout[(size_t)row * HIDF + col] = (ushort)bf_rne(t);
            }
        }
    }
}

// ---------------------------------------------------------------------------
// 6) Final linear: out[N,64] = h(bf16) @ Wout + bout
// ---------------------------------------------------------------------------
__global__ __launch_bounds__(256) void k_final(const uint* __restrict__ h,
                                               const float* __restrict__ Wout,
                                               const float* __restrict__ bout,
                                               float* __restrict__ out) {
    int tid = threadIdx.x;
    int col = tid & 63;
    int row = blockIdx.x * 4 + (tid >> 6);
    if (row >= NNODES) return;
    const uint* hp = h + (size_t)row * (HIDF / 2);
    float acc = bout[col];
#pragma unroll 8
    for (int ku = 0; ku < HIDF / 2; ++ku) {
        uint v = hp[ku];
        acc = fmaf(bf_lo(v), Wout[(2 * ku) * OUTF + col], acc);
        acc = fmaf(bf_hi(v), Wout[(2 * ku + 1) * OUTF + col], acc);
    }
    out[(size_t)row * OUTF + col] = acc;
}

// ---------------------------------------------------------------------------
// Host launcher
// ---------------------------------------------------------------------------
extern "C" void kernel_launch(void* const* d_in, const int* in_sizes, int n_in,
                              void* d_out, int out_size, void* d_ws, size_t ws_size,
                              hipStream_t stream) {
    const float* x    = (const float*)d_in[0];
    const int*   esrc = (const int*)d_in[1];
    const int*   edst = (const int*)d_in[2];
    const float* W0   = (const float*)d_in[3];
    const float* b0   = (const float*)d_in[4];
    const float* Wl   = (const float*)d_in[5];
    const float* bl   = (const float*)d_in[6];
    const float* Wout = (const float*)d_in[7];
    const float* bout = (const float*)d_in[8];
    float* out = (float*)d_out;

    char* ws = (char*)d_ws;
    size_t off = 0;
    auto carve = [&](size_t bytes) {
        size_t p = off;
        off += (bytes + 255) & ~(size_t)255;
        return p;
    };
    const size_t SZ_RN_I = (size_t)RN * 4;
    // sc_out+sc_in are dead after k_merge; aggb (38.4MB) OVERLAYS them.
    size_t o_sc_out  = carve((size_t)NSEG * RN * 4);
    size_t o_sc_in   = carve((size_t)NSEG * RN * 4);
    size_t o_xsoff   = carve((size_t)NSEG * RN * 4);
    size_t o_deg_in  = carve(SZ_RN_I);
    size_t o_out_nrm = carve(SZ_RN_I);
    size_t o_in_nrm  = carve(SZ_RN_I);
    size_t o_row_ptr = carve((size_t)NR * (NNODES + 1) * 4);
    size_t o_csums   = carve((size_t)NR * NCHUNK * 4);
    size_t o_coffs   = carve((size_t)NR * NCHUNK * 4);
    size_t o_csr     = carve((size_t)NR * NE * 8);              // int2 (src, w)
    size_t o_xb      = carve((size_t)NNODES * (HIDF / 2) * 4);  // bf16 packed
    size_t o_h       = carve((size_t)NNODES * (HIDF / 2) * 4);  // bf16 packed
    size_t o_wbT     = carve((size_t)5 * HIDF * KU * 4);        // bf16 W, 5 layers
    (void)ws_size;

    int*    sc_out   = (int*)(ws + o_sc_out);
    int*    sc_in    = (int*)(ws + o_sc_in);
    int*    xsoff    = (int*)(ws + o_xsoff);
    int*    deg_in   = (int*)(ws + o_deg_in);
    float*  out_norm = (float*)(ws + o_out_nrm);
    float*  in_norm  = (float*)(ws + o_in_nrm);
    int*    row_ptr  = (int*)(ws + o_row_ptr);
    int*    csums    = (int*)(ws + o_csums);
    int*    coffs    = (int*)(ws + o_coffs);
    int2*   csr_sw   = (int2*)(ws + o_csr);
    uint*   aggb     = (uint*)(ws + o_sc_out);   // overlay
    uint*   xb       = (uint*)(ws + o_xb);
    uint*   h        = (uint*)(ws + o_h);
    uint*   wbT      = (uint*)(ws + o_wbT);

    // no memset needed: seg_count/merge fully overwrite their outputs

    k_cast_x<<<(NNODES * (HIDF / 2) + 255) / 256, 256, 0, stream>>>(x, xb);
    k_cast_w<<<(5 * HIDF * KU + 255) / 256, 256, 0, stream>>>(W0, Wl, wbT);
    k_seg_count<<<2 * NR * NCH * NSEG, CTH, 0, stream>>>(esrc, edst, sc_out, sc_in);
    k_merge<<<(RN + 255) / 256, 256, 0, stream>>>(sc_out, sc_in, deg_in, xsoff, out_norm, in_norm);
    k_scan1<<<NR * NCHUNK, SCAN_T, 0, stream>>>(deg_in, row_ptr, csums);
    k_scan2<<<1, 64, 0, stream>>>(csums, coffs);
    k_scan3<<<NR * NCHUNK, SCAN_T, 0, stream>>>(row_ptr, coffs);
    k_rpx<<<(NSEG * RN + 255) / 256, 256, 0, stream>>>(row_ptr, xsoff);
    k_seg_fill<<<NR * NCH * NSEG, CTH, 0, stream>>>(esrc, edst, xsoff, out_norm, csr_sw);

    const int aggBlocks = (RN + 3) / 4;
    const int mmBlocks  = (NNODES + 127) / 128;

    const uint* hin = xb;
    for (int l = 0; l < 5; ++l) {
        k_aggregate<<<aggBlocks, 256, 0, stream>>>(hin, in_norm, row_ptr, csr_sw, aggb);
        const uint*  Wp = wbT + (size_t)l * HIDF * KU;
        const float* bp = (l == 0) ? b0 : bl + (size_t)(l - 1) * NR * HIDF;
        k_conv_mm<<<mmBlocks, 256, 0, stream>>>(aggb, Wp, bp, (ushort*)h, (l < 4) ? 1 : 0);
        hin = h;
    }
    k_final<<<(NNODES + 3) / 4, 256, 0, stream>>>(h, Wout, bout, out);
}

// Round 15
// 908.698 us; speedup vs baseline: 1.0608x; 1.0608x over previous
//
#include <hip/hip_runtime.h>
#include <hip/hip_bf16.h>
#include <cstddef>
#include <cstdint>

#define NNODES 50000
#define NR 3
#define NE 800000
#define HIDF 128
#define OUTF 64
#define NEG_SLOPE 0.01f
#define SCAN_T 1024
#define NCHUNK ((NNODES + SCAN_T - 1) / SCAN_T)   // 49
#define KTOT (NR * HIDF)                          // 384
#define KU (KTOT / 2)                             // 192 uints per row
#define RN (NR * NNODES)                          // 150000
#define CHN 25000                                 // chunk node range (100KB u32 LDS)
#define NCH ((NNODES + CHN - 1) / CHN)            // 2
#define CTH 1024                                  // count/fill block size
#define NSEG 32                                   // edge segments
#define SEGE (NE / NSEG)                          // 25000 edges per segment

// bf16 helpers: packed ushort2-in-uint, round-to-nearest-even on pack
__device__ __forceinline__ float bf_lo(uint v) { return __uint_as_float(v << 16); }
__device__ __forceinline__ float bf_hi(uint v) { return __uint_as_float(v & 0xffff0000u); }
__device__ __forceinline__ uint bf_rne(float f) {
    uint u = __float_as_uint(f);
    return (u + 0x7fffu + ((u >> 16) & 1u)) >> 16;
}
__device__ __forceinline__ uint bf_pack(float a, float b) {
    return bf_rne(a) | (bf_rne(b) << 16);
}

typedef short bf16x8 __attribute__((ext_vector_type(8)));
typedef float f32x4 __attribute__((ext_vector_type(4)));
__device__ __forceinline__ bf16x8 as_bf(uint4 v) { return __builtin_bit_cast(bf16x8, v); }

// ---------------------------------------------------------------------------
// 0) Cast x (fp32) -> packed bf16 rows
// ---------------------------------------------------------------------------
__global__ __launch_bounds__(256) void k_cast_x(const float* __restrict__ x,
                                                uint* __restrict__ xb) {
    int i = blockIdx.x * blockDim.x + threadIdx.x;   // uint index: N*64
    if (i >= NNODES * (HIDF / 2)) return;
    float2 v = *(const float2*)(x + (size_t)i * 2);
    xb[i] = bf_pack(v.x, v.y);
}

// ---------------------------------------------------------------------------
// 0b) Cast all 5 layers' W (fp32 [r][k][n]) -> bf16 transposed wbT[l][n][kpair]
// ---------------------------------------------------------------------------
__global__ __launch_bounds__(256) void k_cast_w(const float* __restrict__ W0,
                                                const float* __restrict__ Wl,
                                                uint* __restrict__ wbT) {
    int idx = blockIdx.x * blockDim.x + threadIdx.x;
    if (idx >= 5 * HIDF * KU) return;
    int l = idx / (HIDF * KU);
    int rem = idx - l * (HIDF * KU);
    int t = rem / HIDF;          // uint-k index 0..191
    int n = rem - t * HIDF;      // col, fastest -> coalesced reads
    int r = t / 64;
    int kk = (t - r * 64) * 2;   // even k within relation block
    const float* Wsrc = (l == 0) ? W0 : Wl + (size_t)(l - 1) * NR * HIDF * HIDF;
    const float* wp = Wsrc + ((size_t)r * HIDF + kk) * HIDF + n;
    float a = wp[0];
    float b = wp[HIDF];
    wbT[(size_t)l * HIDF * KU + (size_t)n * KU + t] = bf_pack(a, b);
}

// ---------------------------------------------------------------------------
// 1) Segmented chunk-scan histograms -- NO global atomics (round-9 win).
// ---------------------------------------------------------------------------
__global__ __launch_bounds__(CTH) void k_seg_count(const int* __restrict__ esrc,
                                                   const int* __restrict__ edst,
                                                   int* __restrict__ sc_out,
                                                   int* __restrict__ sc_in) {
    __shared__ int cnt[CHN];
    int bid = blockIdx.x;                    // 0 .. 2*NR*NCH*NSEG-1
    int role = bid / (NR * NCH * NSEG);      // 0: dst counts, 1: src counts
    int rem = bid - role * (NR * NCH * NSEG);
    int r = rem / (NCH * NSEG);
    int rem2 = rem - r * (NCH * NSEG);
    int c = rem2 / NSEG;
    int seg = rem2 - c * NSEG;
    int lo = c * CHN;
    int hi = lo + CHN; if (hi > NNODES) hi = NNODES;
    int span = hi - lo;
    const int* arr = (role ? esrc : edst) + (size_t)r * NE + (size_t)seg * SEGE;

    for (int i = threadIdx.x; i < CHN; i += CTH) cnt[i] = 0;
    __syncthreads();

    int base = threadIdx.x * 4;
    for (int it = 0; it < SEGE; it += CTH * 4) {
        int idx = it + base;
        if (idx < SEGE) {                    // SEGE%4==0 -> full int4 always valid
            int4 v = *(const int4*)(arr + idx);
            if ((unsigned)(v.x - lo) < (unsigned)span) atomicAdd(&cnt[v.x - lo], 1);
            if ((unsigned)(v.y - lo) < (unsigned)span) atomicAdd(&cnt[v.y - lo], 1);
            if ((unsigned)(v.z - lo) < (unsigned)span) atomicAdd(&cnt[v.z - lo], 1);
            if ((unsigned)(v.w - lo) < (unsigned)span) atomicAdd(&cnt[v.w - lo], 1);
        }
    }
    __syncthreads();

    int* dst = (role ? sc_out : sc_in) + (size_t)seg * RN + r * NNODES;
    for (int i = threadIdx.x; i < span; i += CTH) dst[lo + i] = cnt[i];
}

// ---------------------------------------------------------------------------
// 2) Merge segments: deg_in totals, per-(node,seg) exclusive prefix, norms.
// ---------------------------------------------------------------------------
__global__ __launch_bounds__(256) void k_merge(const int* __restrict__ sc_out,
                                               const int* __restrict__ sc_in,
                                               int* __restrict__ deg_in,
                                               int* __restrict__ xsoff,
                                               float* __restrict__ out_norm,
                                               float* __restrict__ in_norm) {
    int idx = blockIdx.x * blockDim.x + threadIdx.x;
    if (idx >= RN) return;
    int so = 0;
#pragma unroll
    for (int s = 0; s < NSEG; ++s) so += sc_out[(size_t)s * RN + idx];
    int si = 0;
#pragma unroll
    for (int s = 0; s < NSEG; ++s) {
        xsoff[(size_t)s * RN + idx] = si;
        si += sc_in[(size_t)s * RN + idx];
    }
    deg_in[idx] = si;
    out_norm[idx] = rsqrtf((float)(so > 1 ? so : 1));
    in_norm[idx]  = rsqrtf((float)(si > 1 ? si : 1));
}

// ---------------------------------------------------------------------------
// 3) CSR build: per-chunk inclusive scan -> chunk sums -> offsets -> add
// ---------------------------------------------------------------------------
__global__ __launch_bounds__(SCAN_T) void k_scan1(const int* __restrict__ deg_in,
                                                  int* __restrict__ row_ptr,
                                                  int* __restrict__ csums) {
    __shared__ int buf[SCAN_T];
    int r = blockIdx.x / NCHUNK;
    int c = blockIdx.x % NCHUNK;
    int tid = threadIdx.x;
    int i = c * SCAN_T + tid;
    int v = (i < NNODES) ? deg_in[r * NNODES + i] : 0;
    buf[tid] = v;
    __syncthreads();
    for (int off = 1; off < SCAN_T; off <<= 1) {
        int t = (tid >= off) ? buf[tid - off] : 0;
        __syncthreads();
        buf[tid] += t;
        __syncthreads();
    }
    if (i < NNODES) row_ptr[r * (NNODES + 1) + i + 1] = buf[tid];
    if (tid == SCAN_T - 1) csums[r * NCHUNK + c] = buf[SCAN_T - 1];
}

__global__ void k_scan2(const int* __restrict__ csums, int* __restrict__ coffs) {
    int r = threadIdx.x;
    if (r >= NR) return;
    int run = 0;
    for (int c = 0; c < NCHUNK; ++c) {
        coffs[r * NCHUNK + c] = run;
        run += csums[r * NCHUNK + c];
    }
}

__global__ __launch_bounds__(SCAN_T) void k_scan3(int* __restrict__ row_ptr,
                                                  const int* __restrict__ coffs) {
    int r = blockIdx.x / NCHUNK;
    int c = blockIdx.x % NCHUNK;
    int tid = threadIdx.x;
    int i = c * SCAN_T + tid;
    int off = coffs[r * NCHUNK + c];
    if (i < NNODES) row_ptr[r * (NNODES + 1) + i + 1] += off;
    if (tid == 0 && c == 0) row_ptr[r * (NNODES + 1)] = 0;
}

// ---------------------------------------------------------------------------
// 3c) Fuse row_ptr into xsoff (in-place): xsoff[seg][r][n] += row_ptr[r][n].
// ---------------------------------------------------------------------------
__global__ __launch_bounds__(256) void k_rpx(const int* __restrict__ row_ptr,
                                             int* __restrict__ xsoff) {
    int idx = blockIdx.x * blockDim.x + threadIdx.x;   // over NSEG*RN
    if (idx >= NSEG * RN) return;
    int rn = idx % RN;
    int r = rn / NNODES;
    int n = rn - r * NNODES;
    xsoff[idx] += row_ptr[r * (NNODES + 1) + n];
}

// ---------------------------------------------------------------------------
// 3b) Segmented chunk-scan CSR fill -- atomic-free.
//     slot = rpx[seg][d] + LDS-counter position. Writes (src, out_norm[src]).
// ---------------------------------------------------------------------------
__global__ __launch_bounds__(CTH) void k_seg_fill(const int* __restrict__ esrc,
                                                  const int* __restrict__ edst,
                                                  const int* __restrict__ rpx,
                                                  const float* __restrict__ out_norm,
                                                  int2* __restrict__ csr_sw) {
    __shared__ int cur[CHN];
    int bid = blockIdx.x;                    // 0 .. NR*NCH*NSEG-1
    int r = bid / (NCH * NSEG);
    int rem = bid - r * (NCH * NSEG);
    int c = rem / NSEG;
    int seg = rem - c * NSEG;
    int lo = c * CHN;
    int hi = lo + CHN; if (hi > NNODES) hi = NNODES;
    int span = hi - lo;
    const int* sarr = esrc + (size_t)r * NE + (size_t)seg * SEGE;
    const int* darr = edst + (size_t)r * NE + (size_t)seg * SEGE;
    const int* xs = rpx + (size_t)seg * RN + r * NNODES;
    const float* on = out_norm + r * NNODES;
    int2* cs = csr_sw + (size_t)r * NE;

    for (int i = threadIdx.x; i < CHN; i += CTH) cur[i] = 0;
    __syncthreads();

    int base = threadIdx.x * 4;
    for (int it = 0; it < SEGE; it += CTH * 4) {
        int idx = it + base;
        if (idx < SEGE) {
            int4 d = *(const int4*)(darr + idx);
            int4 s = *(const int4*)(sarr + idx);
            if ((unsigned)(d.x - lo) < (unsigned)span) {
                int p = atomicAdd(&cur[d.x - lo], 1);
                cs[xs[d.x] + p] = make_int2(s.x, __float_as_int(on[s.x]));
            }
            if ((unsigned)(d.y - lo) < (unsigned)span) {
                int p = atomicAdd(&cur[d.y - lo], 1);
                cs[xs[d.y] + p] = make_int2(s.y, __float_as_int(on[s.y]));
            }
            if ((unsigned)(d.z - lo) < (unsigned)span) {
                int p = atomicAdd(&cur[d.z - lo], 1);
                cs[xs[d.z] + p] = make_int2(s.z, __float_as_int(on[s.z]));
            }
            if ((unsigned)(d.w - lo) < (unsigned)span) {
                int p = atomicAdd(&cur[d.w - lo], 1);
                cs[xs[d.w] + p] = make_int2(s.w, __float_as_int(on[s.w]));
            }
        }
    }
}

// ---------------------------------------------------------------------------
// 4) Aggregation (round-9 shape -- at its measured mixed L3+HBM roofline:
//    FETCH 233MB, 3.4TB/s HBM + ~5TB/s L3, VALU 60%, Occ 74%). Round-14
//    lesson: nt-hints on the csr stream HURT (sequential stream relies on
//    L2 hits); round-10 lesson: quarter-split pushed gathers to HBM. Keep.
// ---------------------------------------------------------------------------
__global__ __launch_bounds__(256) void k_aggregate(const uint* __restrict__ hin,
                                                   const float* __restrict__ in_norm,
                                                   const int* __restrict__ row_ptr,
                                                   const int2* __restrict__ csr_sw,
                                                   uint* __restrict__ aggb) {
    int wave = blockIdx.x * 4 + (threadIdx.x >> 6);
    if (wave >= RN) return;
    int r = wave / NNODES;
    int n = wave - r * NNODES;
    int lane = threadIdx.x & 63;
    int quarter = lane >> 4;
    int sub = lane & 15;
    int start = row_ptr[r * (NNODES + 1) + n];
    int end   = row_ptr[r * (NNODES + 1) + n + 1];
    const int2* cw = csr_sw + (size_t)r * NE;

    float acc[8];
#pragma unroll
    for (int k = 0; k < 8; ++k) acc[k] = 0.f;

    int i = start;
    int last = end - 1;
    for (; i + 16 <= end; i += 16) {
        int2 e0 = cw[i + quarter];
        int2 e1 = cw[i + 4 + quarter];
        int2 e2 = cw[i + 8 + quarter];
        int2 e3 = cw[i + 12 + quarter];
        uint4 v0 = *(const uint4*)(hin + (size_t)e0.x * (HIDF / 2) + sub * 4);
        uint4 v1 = *(const uint4*)(hin + (size_t)e1.x * (HIDF / 2) + sub * 4);
        uint4 v2 = *(const uint4*)(hin + (size_t)e2.x * (HIDF / 2) + sub * 4);
        uint4 v3 = *(const uint4*)(hin + (size_t)e3.x * (HIDF / 2) + sub * 4);
        float w0 = __int_as_float(e0.y);
        float w1 = __int_as_float(e1.y);
        float w2 = __int_as_float(e2.y);
        float w3 = __int_as_float(e3.y);
        acc[0] = fmaf(w0, bf_lo(v0.x), acc[0]); acc[1] = fmaf(w0, bf_hi(v0.x), acc[1]);
        acc[2] = fmaf(w0, bf_lo(v0.y), acc[2]); acc[3] = fmaf(w0, bf_hi(v0.y), acc[3]);
        acc[4] = fmaf(w0, bf_lo(v0.z), acc[4]); acc[5] = fmaf(w0, bf_hi(v0.z), acc[5]);
        acc[6] = fmaf(w0, bf_lo(v0.w), acc[6]); acc[7] = fmaf(w0, bf_hi(v0.w), acc[7]);
        acc[0] = fmaf(w1, bf_lo(v1.x), acc[0]); acc[1] = fmaf(w1, bf_hi(v1.x), acc[1]);
        acc[2] = fmaf(w1, bf_lo(v1.y), acc[2]); acc[3] = fmaf(w1, bf_hi(v1.y), acc[3]);
        acc[4] = fmaf(w1, bf_lo(v1.z), acc[4]); acc[5] = fmaf(w1, bf_hi(v1.z), acc[5]);
        acc[6] = fmaf(w1, bf_lo(v1.w), acc[6]); acc[7] = fmaf(w1, bf_hi(v1.w), acc[7]);
        acc[0] = fmaf(w2, bf_lo(v2.x), acc[0]); acc[1] = fmaf(w2, bf_hi(v2.x), acc[1]);
        acc[2] = fmaf(w2, bf_lo(v2.y), acc[2]); acc[3] = fmaf(w2, bf_hi(v2.y), acc[3]);
        acc[4] = fmaf(w2, bf_lo(v2.z), acc[4]); acc[5] = fmaf(w2, bf_hi(v2.z), acc[5]);
        acc[6] = fmaf(w2, bf_lo(v2.w), acc[6]); acc[7] = fmaf(w2, bf_hi(v2.w), acc[7]);
        acc[0] = fmaf(w3, bf_lo(v3.x), acc[0]); acc[1] = fmaf(w3, bf_hi(v3.x), acc[1]);
        acc[2] = fmaf(w3, bf_lo(v3.y), acc[2]); acc[3] = fmaf(w3, bf_hi(v3.y), acc[3]);
        acc[4] = fmaf(w3, bf_lo(v3.z), acc[4]); acc[5] = fmaf(w3, bf_hi(v3.z), acc[5]);
        acc[6] = fmaf(w3, bf_lo(v3.w), acc[6]); acc[7] = fmaf(w3, bf_hi(v3.w), acc[7]);
    }
    for (; i + 8 <= end; i += 8) {
        int2 eA = cw[i + quarter];
        int2 eB = cw[i + 4 + quarter];
        uint4 vA = *(const uint4*)(hin + (size_t)eA.x * (HIDF / 2) + sub * 4);
        uint4 vB = *(const uint4*)(hin + (size_t)eB.x * (HIDF / 2) + sub * 4);
        float wA = __int_as_float(eA.y);
        float wB = __int_as_float(eB.y);
        acc[0] = fmaf(wA, bf_lo(vA.x), acc[0]); acc[1] = fmaf(wA, bf_hi(vA.x), acc[1]);
        acc[2] = fmaf(wA, bf_lo(vA.y), acc[2]); acc[3] = fmaf(wA, bf_hi(vA.y), acc[3]);
        acc[4] = fmaf(wA, bf_lo(vA.z), acc[4]); acc[5] = fmaf(wA, bf_hi(vA.z), acc[5]);
        acc[6] = fmaf(wA, bf_lo(vA.w), acc[6]); acc[7] = fmaf(wA, bf_hi(vA.w), acc[7]);
        acc[0] = fmaf(wB, bf_lo(vB.x), acc[0]); acc[1] = fmaf(wB, bf_hi(vB.x), acc[1]);
        acc[2] = fmaf(wB, bf_lo(vB.y), acc[2]); acc[3] = fmaf(wB, bf_hi(vB.y), acc[3]);
        acc[4] = fmaf(wB, bf_lo(vB.z), acc[4]); acc[5] = fmaf(wB, bf_hi(vB.z), acc[5]);
        acc[6] = fmaf(wB, bf_lo(vB.w), acc[6]); acc[7] = fmaf(wB, bf_hi(vB.w), acc[7]);
    }
    for (; i < end; i += 4) {
        int e_idx = i + quarter;
        bool live = e_idx < end;
        int2 e = cw[live ? e_idx : last];
        float w = live ? __int_as_float(e.y) : 0.f;
        uint4 v = *(const uint4*)(hin + (size_t)e.x * (HIDF / 2) + sub * 4);
        acc[0] = fmaf(w, bf_lo(v.x), acc[0]); acc[1] = fmaf(w, bf_hi(v.x), acc[1]);
        acc[2] = fmaf(w, bf_lo(v.y), acc[2]); acc[3] = fmaf(w, bf_hi(v.y), acc[3]);
        acc[4] = fmaf(w, bf_lo(v.z), acc[4]); acc[5] = fmaf(w, bf_hi(v.z), acc[5]);
        acc[6] = fmaf(w, bf_lo(v.w), acc[6]); acc[7] = fmaf(w, bf_hi(v.w), acc[7]);
    }

    // reduce across the 4 quarters (feats identical at same sub)
#pragma unroll
    for (int k = 0; k < 8; ++k) {
        acc[k] += __shfl_xor(acc[k], 16);
        acc[k] += __shfl_xor(acc[k], 32);
    }

    if (quarter == 0) {
        float wn = in_norm[r * NNODES + n];
        uint4 pk;
        pk.x = bf_pack(acc[0] * wn, acc[1] * wn);
        pk.y = bf_pack(acc[2] * wn, acc[3] * wn);
        pk.z = bf_pack(acc[4] * wn, acc[5] * wn);
        pk.w = bf_pack(acc[6] * wn, acc[7] * wn);
        *(uint4*)(aggb + (size_t)n * KU + r * (HIDF / 2) + sub * 4) = pk;
    }
}

// ---------------------------------------------------------------------------
// 5) Per-layer matmul, bf16 MFMA (direct-global fragments, no LDS):
//    h = act( (1/3) * aggb[N,384] @ wbT^T + bmean ), output row-major u16 bf16.
// ---------------------------------------------------------------------------
__global__ __launch_bounds__(256) void k_conv_mm(const uint* __restrict__ aggb,
                                                 const uint* __restrict__ wbT,
                                                 const float* __restrict__ bias,
                                                 ushort* __restrict__ hout,
                                                 int act) {
    int wv   = threadIdx.x >> 6;
    int lane = threadIdx.x & 63;
    int lrow = lane & 15;
    int kgrp = lane >> 4;
    int rb = blockIdx.x * 128 + wv * 32;

    f32x4 acc[2][8];
#pragma unroll
    for (int m = 0; m < 2; ++m)
#pragma unroll
        for (int nr = 0; nr < 8; ++nr) acc[m][nr] = (f32x4){0.f, 0.f, 0.f, 0.f};

    int row0 = rb + lrow;
    int row1 = rb + 16 + lrow;
    bool v0 = row0 < NNODES;
    bool v1 = row1 < NNODES;
    const uint* a0p = aggb + (size_t)row0 * KU + kgrp * 4;
    const uint* a1p = aggb + (size_t)row1 * KU + kgrp * 4;
    const uint* bp  = wbT + (size_t)lrow * KU + kgrp * 4;
    const uint4 za = make_uint4(0u, 0u, 0u, 0u);

#pragma unroll
    for (int ks = 0; ks < KTOT / 32; ++ks) {
        uint4 ua0 = v0 ? *(const uint4*)(a0p + ks * 16) : za;
        uint4 ua1 = v1 ? *(const uint4*)(a1p + ks * 16) : za;
        bf16x8 af0 = as_bf(ua0);
        bf16x8 af1 = as_bf(ua1);
#pragma unroll
        for (int nr = 0; nr < 8; ++nr) {
            uint4 ub = *(const uint4*)(bp + (size_t)nr * (16 * KU) + ks * 16);
            bf16x8 bf = as_bf(ub);
            acc[0][nr] = __builtin_amdgcn_mfma_f32_16x16x32_bf16(af0, bf, acc[0][nr], 0, 0, 0);
            acc[1][nr] = __builtin_amdgcn_mfma_f32_16x16x32_bf16(af1, bf, acc[1][nr], 0, 0, 0);
        }
    }

    const float inv3 = 1.f / 3.f;
#pragma unroll
    for (int nr = 0; nr < 8; ++nr) {
        int col = nr * 16 + lrow;
        float bm = (bias[col] + bias[HIDF + col] + bias[2 * HIDF + col]) * inv3;
#pragma unroll
        for (int m = 0; m < 2; ++m) {
            int rbase = rb + m * 16 + kgrp * 4;
#pragma unroll
            for (int i = 0; i < 4; ++i) {
                int row = rbase + i;
                if (row >= NNODES) continue;
                float t = acc[m][nr][i] * inv3 + bm;
                if (act) t = (t > 0.f) ? t : NEG_SLOPE * t;
                hout[(size_t)row * HIDF + col] = (ushort)bf_rne(t);
            }
        }
    }
}

// ---------------------------------------------------------------------------
// 6) Final linear: out[N,64] = h(bf16) @ Wout + bout
// ---------------------------------------------------------------------------
__global__ __launch_bounds__(256) void k_final(const uint* __restrict__ h,
                                               const float* __restrict__ Wout,
                                               const float* __restrict__ bout,
                                               float* __restrict__ out) {
    int tid = threadIdx.x;
    int col = tid & 63;
    int row = blockIdx.x * 4 + (tid >> 6);
    if (row >= NNODES) return;
    const uint* hp = h + (size_t)row * (HIDF / 2);
    float acc = bout[col];
#pragma unroll 8
    for (int ku = 0; ku < HIDF / 2; ++ku) {
        uint v = hp[ku];
        acc = fmaf(bf_lo(v), Wout[(2 * ku) * OUTF + col], acc);
        acc = fmaf(bf_hi(v), Wout[(2 * ku + 1) * OUTF + col], acc);
    }
    out[(size_t)row * OUTF + col] = acc;
}

// ---------------------------------------------------------------------------
// Host launcher
// ---------------------------------------------------------------------------
extern "C" void kernel_launch(void* const* d_in, const int* in_sizes, int n_in,
                              void* d_out, int out_size, void* d_ws, size_t ws_size,
                              hipStream_t stream) {
    const float* x    = (const float*)d_in[0];
    const int*   esrc = (const int*)d_in[1];
    const int*   edst = (const int*)d_in[2];
    const float* W0   = (const float*)d_in[3];
    const float* b0   = (const float*)d_in[4];
    const float* Wl   = (const float*)d_in[5];
    const float* bl   = (const float*)d_in[6];
    const float* Wout = (const float*)d_in[7];
    const float* bout = (const float*)d_in[8];
    float* out = (float*)d_out;

    char* ws = (char*)d_ws;
    size_t off = 0;
    auto carve = [&](size_t bytes) {
        size_t p = off;
        off += (bytes + 255) & ~(size_t)255;
        return p;
    };
    const size_t SZ_RN_I = (size_t)RN * 4;
    // sc_out+sc_in are dead after k_merge; aggb (38.4MB) OVERLAYS them.
    size_t o_sc_out  = carve((size_t)NSEG * RN * 4);
    size_t o_sc_in   = carve((size_t)NSEG * RN * 4);
    size_t o_xsoff   = carve((size_t)NSEG * RN * 4);
    size_t o_deg_in  = carve(SZ_RN_I);
    size_t o_out_nrm = carve(SZ_RN_I);
    size_t o_in_nrm  = carve(SZ_RN_I);
    size_t o_row_ptr = carve((size_t)NR * (NNODES + 1) * 4);
    size_t o_csums   = carve((size_t)NR * NCHUNK * 4);
    size_t o_coffs   = carve((size_t)NR * NCHUNK * 4);
    size_t o_csr     = carve((size_t)NR * NE * 8);              // int2 (src, w)
    size_t o_xb      = carve((size_t)NNODES * (HIDF / 2) * 4);  // bf16 packed
    size_t o_h       = carve((size_t)NNODES * (HIDF / 2) * 4);  // bf16 packed
    size_t o_wbT     = carve((size_t)5 * HIDF * KU * 4);        // bf16 W, 5 layers
    (void)ws_size;

    int*    sc_out   = (int*)(ws + o_sc_out);
    int*    sc_in    = (int*)(ws + o_sc_in);
    int*    xsoff    = (int*)(ws + o_xsoff);
    int*    deg_in   = (int*)(ws + o_deg_in);
    float*  out_norm = (float*)(ws + o_out_nrm);
    float*  in_norm  = (float*)(ws + o_in_nrm);
    int*    row_ptr  = (int*)(ws + o_row_ptr);
    int*    csums    = (int*)(ws + o_csums);
    int*    coffs    = (int*)(ws + o_coffs);
    int2*   csr_sw   = (int2*)(ws + o_csr);
    uint*   aggb     = (uint*)(ws + o_sc_out);   // overlay
    uint*   xb       = (uint*)(ws + o_xb);
    uint*   h        = (uint*)(ws + o_h);
    uint*   wbT      = (uint*)(ws + o_wbT);

    // no memset needed: seg_count/merge fully overwrite their outputs

    k_cast_x<<<(NNODES * (HIDF / 2) + 255) / 256, 256, 0, stream>>>(x, xb);
    k_cast_w<<<(5 * HIDF * KU + 255) / 256, 256, 0, stream>>>(W0, Wl, wbT);
    k_seg_count<<<2 * NR * NCH * NSEG, CTH, 0, stream>>>(esrc, edst, sc_out, sc_in);
    k_merge<<<(RN + 255) / 256, 256, 0, stream>>>(sc_out, sc_in, deg_in, xsoff, out_norm, in_norm);
    k_scan1<<<NR * NCHUNK, SCAN_T, 0, stream>>>(deg_in, row_ptr, csums);
    k_scan2<<<1, 64, 0, stream>>>(csums, coffs);
    k_scan3<<<NR * NCHUNK, SCAN_T, 0, stream>>>(row_ptr, coffs);
    k_rpx<<<(NSEG * RN + 255) / 256, 256, 0, stream>>>(row_ptr, xsoff);
    k_seg_fill<<<NR * NCH * NSEG, CTH, 0, stream>>>(esrc, edst, xsoff, out_norm, csr_sw);

    const int aggBlocks = (RN + 3) / 4;
    const int mmBlocks  = (NNODES + 127) / 128;

    const uint* hin = xb;
    for (int l = 0; l < 5; ++l) {
        k_aggregate<<<aggBlocks, 256, 0, stream>>>(hin, in_norm, row_ptr, csr_sw, aggb);
        const uint*  Wp = wbT + (size_t)l * HIDF * KU;
        const float* bp = (l == 0) ? b0 : bl + (size_t)(l - 1) * NR * HIDF;
        k_conv_mm<<<mmBlocks, 256, 0, stream>>>(aggb, Wp, bp, (ushort*)h, (l < 4) ? 1 : 0);
        hin = h;
    }
    k_final<<<(NNODES + 3) / 4, 256, 0, stream>>>(h, Wout, bout, out);
}